// Round 1
// baseline (83.910 us; speedup 1.0000x reference)
//
#include <hip/hip_runtime.h>
#include <hip/hip_bf16.h>

// Dendritic net forward: B=1024, L=4, D=32, S=10, M=2^10-1=1023.
// Key identity: exp(mask @ log s) over all 1023 nonempty subsets == subset
// products of the 10 sigmoids. Split 10 bits into low-5/high-5 halves:
// feat[v] = pl[v&31] * ph[v>>5]; dend = sum_v dend_w[v-1]*feat[v] factors as
// sum_vh ph[vh] * (sum_vl dend_w[vh*32+vl-1] * pl[vl]).
//
// Wave layout: wave index == layer l (readfirstlane -> SGPR so dend_w row
// loads become s_load, feeding v_fmac v,s,v). Lanes: [b_local(2) x d(32)].
// Block = 256 thr = 2 batches x 4 layers. Grid = B/2 = 512 blocks.

#define NS 10

__global__ __launch_bounds__(256) void dendrite_fwd(
    const float* __restrict__ x,        // (B,1,S)
    const float* __restrict__ k,        // (L,D,S)
    const float* __restrict__ w,        // (L,D,S)
    const float* __restrict__ q,        // (L,D,S)
    const float* __restrict__ dend_w,   // (L,M)
    const float* __restrict__ dend_b,   // (L,)
    const float* __restrict__ lin_w,    // (L,D)
    const float* __restrict__ lin_b,    // (L,)
    const float* __restrict__ final_w,  // (L,)
    const float* __restrict__ final_b,  // (1,)
    const float* __restrict__ ks,       // (1,)
    float* __restrict__ out)            // (B,)
{
    const int lane = threadIdx.x & 63;
    const int wv   = threadIdx.x >> 6;                       // 0..3
    const int l    = __builtin_amdgcn_readfirstlane(wv);     // wave-uniform layer
    const int d    = lane & 31;
    const int bl   = lane >> 5;                              // batch-local 0/1
    const int b    = blockIdx.x * 2 + bl;

    const float* kp = k + (l * 32 + d) * NS;
    const float* wp = w + (l * 32 + d) * NS;
    const float* qp = q + (l * 32 + d) * NS;
    const float* xp = x + b * NS;

    // t[i] multiplies into subsets whose bit i is set; bit i of v corresponds
    // to mask column (9-i) (MSB-first binary expansion) -> t[i] = s[9-i].
    float t[NS];
#pragma unroll
    for (int i = 0; i < NS; ++i) {
        float z = kp[i] * (wp[i] * xp[i] - qp[i]);
        float s = 1.0f / (1.0f + __expf(-z));
        t[NS - 1 - i] = s;
    }

    // All 32 subset products of t[0..4] and of t[5..9].
    float pl[32], ph[32];
    pl[0] = 1.0f;
    ph[0] = 1.0f;
#pragma unroll
    for (int v = 1; v < 32; ++v) {
        pl[v] = pl[v & (v - 1)] * t[__builtin_ctz(v)];
        ph[v] = ph[v & (v - 1)] * t[5 + __builtin_ctz(v)];
    }

    const float* dw = dend_w + l * 1023;  // uniform base -> scalar loads

    float acc;
    {   // vh == 0: v = vl, vl = 1..31, dend_w index v-1; ph[0] == 1.
        float i0 = 0.f, i1 = 0.f, i2 = 0.f, i3 = 0.f;
#pragma unroll
        for (int vl = 1; vl < 32; vl += 4) {
            i0 = fmaf(dw[vl - 1], pl[vl], i0);
            if (vl + 1 < 32) i1 = fmaf(dw[vl + 0], pl[vl + 1], i1);
            if (vl + 2 < 32) i2 = fmaf(dw[vl + 1], pl[vl + 2], i2);
            if (vl + 3 < 32) i3 = fmaf(dw[vl + 2], pl[vl + 3], i3);
        }
        acc = (i0 + i1) + (i2 + i3);
    }
#pragma unroll
    for (int vh = 1; vh < 32; ++vh) {
        const float* dwr = dw + vh * 32 - 1;  // index v-1 = vh*32+vl-1
        float i0 = 0.f, i1 = 0.f, i2 = 0.f, i3 = 0.f;
#pragma unroll
        for (int j = 0; j < 8; ++j) {
            i0 = fmaf(dwr[4 * j + 0], pl[4 * j + 0], i0);
            i1 = fmaf(dwr[4 * j + 1], pl[4 * j + 1], i1);
            i2 = fmaf(dwr[4 * j + 2], pl[4 * j + 2], i2);
            i3 = fmaf(dwr[4 * j + 3], pl[4 * j + 3], i3);
        }
        acc = fmaf(ph[vh], (i0 + i1) + (i2 + i3), acc);
    }

    // dend(b,l,d) -> out(b,l) via lin_w, then scale by final_w for the l-sum.
    float contrib = (acc + dend_b[l]) * lin_w[l * 32 + d];
#pragma unroll
    for (int off = 16; off >= 1; off >>= 1)
        contrib += __shfl_xor(contrib, off, 64);  // sum over 32 d-lanes

    __shared__ float red[4][2];
    if (d == 0)
        red[wv][bl] = (contrib + lin_b[l]) * final_w[l];
    __syncthreads();

    if (threadIdx.x < 2) {
        float fin = red[0][threadIdx.x] + red[1][threadIdx.x] +
                    red[2][threadIdx.x] + red[3][threadIdx.x] + final_b[0];
        out[blockIdx.x * 2 + threadIdx.x] = 1.0f / (1.0f + __expf(-ks[0] * fin));
    }
}

extern "C" void kernel_launch(void* const* d_in, const int* in_sizes, int n_in,
                              void* d_out, int out_size, void* d_ws, size_t ws_size,
                              hipStream_t stream) {
    const float* x       = (const float*)d_in[0];
    const float* k       = (const float*)d_in[1];
    const float* w       = (const float*)d_in[2];
    const float* q       = (const float*)d_in[3];
    const float* dend_w  = (const float*)d_in[4];
    const float* dend_b  = (const float*)d_in[5];
    const float* lin_w   = (const float*)d_in[6];
    const float* lin_b   = (const float*)d_in[7];
    const float* final_w = (const float*)d_in[8];
    const float* final_b = (const float*)d_in[9];
    const float* ksp     = (const float*)d_in[10];
    float* out           = (float*)d_out;

    dendrite_fwd<<<512, 256, 0, stream>>>(x, k, w, q, dend_w, dend_b,
                                          lin_w, lin_b, final_w, final_b,
                                          ksp, out);
}

// Round 2
// 80.518 us; speedup vs baseline: 1.0421x; 1.0421x over previous
//
#include <hip/hip_runtime.h>
#include <hip/hip_bf16.h>

// Dendritic net forward: B=1024, L=4, D=32, S=10, M=2^10-1=1023.
// exp(mask @ log s) over all 1023 nonempty subsets == subset products of the
// 10 sigmoids. feat[v] = pl[v&31]*ph[v>>5]; dend factors as
// sum_vh ph[vh] * (sum_vl dend_w[vh*32+vl-1] * pl[vl]).
//
// R2 layout: block = 256 thr = 4 waves = 4 layers x 1 batch. Grid = B = 1024.
// Wave wv handles layer l=wv (readfirstlane -> uniform). Lane = d(32) + 32*h;
// half h owns vh in [h*16, h*16+16) -> per-thread chain 528 FMAs (was 1056),
// 4096 waves total (4/SIMD, was 2) for latency hiding.
// dend_w staged in LDS [4][1024] (entry 0 zeroed so the v=0 term vanishes);
// ds_read_b128 with only 2 distinct addrs/wave (h=0,h=1) -> broadcast, free.

#define NS 10

__global__ __launch_bounds__(256) void dendrite_fwd(
    const float* __restrict__ x,        // (B,1,S)
    const float* __restrict__ k,        // (L,D,S)
    const float* __restrict__ w,        // (L,D,S)
    const float* __restrict__ q,        // (L,D,S)
    const float* __restrict__ dend_w,   // (L,M)
    const float* __restrict__ dend_b,   // (L,)
    const float* __restrict__ lin_w,    // (L,D)
    const float* __restrict__ lin_b,    // (L,)
    const float* __restrict__ final_w,  // (L,)
    const float* __restrict__ final_b,  // (1,)
    const float* __restrict__ ks,       // (1,)
    float* __restrict__ out)            // (B,)
{
    __shared__ float dwl[4 * 1024];     // [l][v], v=0 is zero pad
    __shared__ float red[4];

    const int tid  = threadIdx.x;
    const int lane = tid & 63;
    const int wv   = tid >> 6;                               // 0..3
    const int l    = __builtin_amdgcn_readfirstlane(wv);     // wave-uniform layer
    const int d    = lane & 31;
    const int h    = lane >> 5;                              // vh-half 0/1
    const int b    = blockIdx.x;

    // ---- stage dend_w -> LDS: dwl[l*1024 + (v)] = dend_w[l*1023 + v-1] ----
    if (tid < 4) dwl[tid * 1024] = 0.0f;
#pragma unroll
    for (int it = 0; it < 16; ++it) {
        int j = tid + it * 256;                // 0..4095
        if (j < 4 * 1023) {
            int lj = j / 1023;                 // magic-mul div
            int r  = j - lj * 1023;
            dwl[lj * 1024 + r + 1] = dend_w[j];
        }
    }

    // ---- sigmoids (independent of LDS staging; overlaps the barrier) ----
    const float* kp = k + (l * 32 + d) * NS;
    const float* wp = w + (l * 32 + d) * NS;
    const float* qp = q + (l * 32 + d) * NS;
    const float* xp = x + b * NS;

    // bit i of v corresponds to mask column (9-i) (MSB-first) -> t[i]=s[9-i]
    float t[NS];
#pragma unroll
    for (int i = 0; i < NS; ++i) {
        float z = kp[i] * (wp[i] * xp[i] - qp[i]);
        t[NS - 1 - i] = 1.0f / (1.0f + __expf(-z));
    }

    // all 32 low-half subset products (compile-time indices only)
    float pl[32];
    pl[0] = 1.0f;
#pragma unroll
    for (int v = 1; v < 32; ++v)
        pl[v] = pl[v & (v - 1)] * t[__builtin_ctz(v)];

    // the 16 high-half products this half-wave owns: vh = h*16 + u.
    // bit4 of vh (==h) -> t[9]; bits0..3 of u -> t[5..8].
    float ph[16];
    ph[0] = h ? t[9] : 1.0f;
#pragma unroll
    for (int u = 1; u < 16; ++u)
        ph[u] = ph[u & (u - 1)] * t[5 + __builtin_ctz(u)];

    __syncthreads();

    // ---- main reduction: acc = sum_u ph[u] * (dwl row . pl) ----
    const float4* row4 = (const float4*)(dwl + l * 1024 + h * 16 * 32);
    float acc = 0.0f;
#pragma unroll
    for (int u = 0; u < 16; ++u) {
        float i0 = 0.f, i1 = 0.f, i2 = 0.f, i3 = 0.f;
#pragma unroll
        for (int j = 0; j < 8; ++j) {
            float4 c = row4[u * 8 + j];
            i0 = fmaf(c.x, pl[4 * j + 0], i0);
            i1 = fmaf(c.y, pl[4 * j + 1], i1);
            i2 = fmaf(c.z, pl[4 * j + 2], i2);
            i3 = fmaf(c.w, pl[4 * j + 3], i3);
        }
        acc = fmaf(ph[u], (i0 + i1) + (i2 + i3), acc);
    }

    // ---- epilogue ----
    // Full-wave butterfly over (acc_half + dend_b/2)*lin_w sums both halves
    // and all d: sum_{d,h} (acc(d,h) + 0.5*dend_b)*lin_w(d)
    //          = sum_d (dend_full(d) + dend_b)*lin_w(d).
    float contrib = (acc + 0.5f * dend_b[l]) * lin_w[l * 32 + d];
#pragma unroll
    for (int off = 32; off >= 1; off >>= 1)
        contrib += __shfl_xor(contrib, off, 64);

    if (lane == 0)
        red[wv] = (contrib + lin_b[l]) * final_w[l];
    __syncthreads();

    if (tid == 0) {
        float fin = red[0] + red[1] + red[2] + red[3] + final_b[0];
        out[b] = 1.0f / (1.0f + __expf(-ks[0] * fin));
    }
}

extern "C" void kernel_launch(void* const* d_in, const int* in_sizes, int n_in,
                              void* d_out, int out_size, void* d_ws, size_t ws_size,
                              hipStream_t stream) {
    const float* x       = (const float*)d_in[0];
    const float* k       = (const float*)d_in[1];
    const float* w       = (const float*)d_in[2];
    const float* q       = (const float*)d_in[3];
    const float* dend_w  = (const float*)d_in[4];
    const float* dend_b  = (const float*)d_in[5];
    const float* lin_w   = (const float*)d_in[6];
    const float* lin_b   = (const float*)d_in[7];
    const float* final_w = (const float*)d_in[8];
    const float* final_b = (const float*)d_in[9];
    const float* ksp     = (const float*)d_in[10];
    float* out           = (float*)d_out;

    dendrite_fwd<<<1024, 256, 0, stream>>>(x, k, w, q, dend_w, dend_b,
                                           lin_w, lin_b, final_w, final_b,
                                           ksp, out);
}